// Round 14
// baseline (303.977 us; speedup 1.0000x reference)
//
#include <hip/hip_runtime.h>
#include <hip/hip_bf16.h>

typedef __bf16 bf16_t;
typedef __bf16 v8bf __attribute__((ext_vector_type(8)));
typedef __bf16 v2bf __attribute__((ext_vector_type(2)));
typedef __bf16 v4bf __attribute__((ext_vector_type(4)));
typedef float  v16f __attribute__((ext_vector_type(16)));

#define NSC   128   // scalar channels
#define NVC   64    // vector channels
#define DDIM  320   // NSC + 3*NVC
#define HIDN  128
#define WNUM  384
#define S0STR 328   // s0 tile stride (656B rows, 16B-aligned)
#define HSTR  136   // h1/h2 stride (272B rows, 16B-aligned)
#define GNB   8     // nodes per gather block

__device__ __forceinline__ float siluf(float x) { return x / (1.f + __expf(-x)); }

// ---------------- weight conversion (32x32x16 fragments) + recv histogram ----------------
// B-fragment (32x32x16): lane l holds col n = nt*32 + (l&31), k = kbase + (l>>5)*8 .. +8.
// p1: [kc 0..19][nt 0..3] ; p3: [kc 0..1][nt] ; p2/p4: [ch][kc 0..7][nt]
__global__ void k_wconv(const float* __restrict__ esw1, const float* __restrict__ esw2,
                        const float* __restrict__ erw1, const float* __restrict__ erw2,
                        bf16_t* __restrict__ p1, bf16_t* __restrict__ p2,
                        bf16_t* __restrict__ p3, bf16_t* __restrict__ p4,
                        const int* __restrict__ eidx, int* __restrict__ hist, int E)
{
    const int gid = blockIdx.x * blockDim.x + threadIdx.x;
    const int stride = gridDim.x * blockDim.x;
    for (int i = gid; i < 80*512; i += stride) {
        int frag = i >> 9, q = i & 511, lane = q >> 3, j = q & 7;
        int kc = frag >> 2, nt = frag & 3;
        int n = nt*32 + (lane & 31), k = kc*16 + (lane >> 5)*8 + j;
        p1[i] = (bf16_t)esw1[k*128 + n];
    }
    for (int i = gid; i < 8*512; i += stride) {
        int frag = i >> 9, q = i & 511, lane = q >> 3, j = q & 7;
        int kc = frag >> 2, nt = frag & 3;
        int n = nt*32 + (lane & 31), k = kc*16 + (lane >> 5)*8 + j;
        p3[i] = (k < 20) ? (bf16_t)erw1[k*128 + n] : (bf16_t)(0.f);
    }
    for (int i = gid; i < 96*512; i += stride) {
        int frag = i >> 9, q = i & 511, lane = q >> 3, j = q & 7;
        int ch = frag >> 5, kc = (frag >> 2) & 7, nt = frag & 3;
        int n = ch*128 + nt*32 + (lane & 31), k = kc*16 + (lane >> 5)*8 + j;
        p2[i] = (bf16_t)esw2[k*384 + n];
        p4[i] = (bf16_t)erw2[k*384 + n];
    }
    for (int e = gid; e < E; e += stride)
        atomicAdd(&hist[eidx[e]], 1);
}

__global__ __launch_bounds__(1024) void k_scan(const int* __restrict__ hist,
                                               int* __restrict__ off, int* __restrict__ cnt, int N)
{
    __shared__ int part[1024];
    const int tid = threadIdx.x;
    const int C = (N + 1023) >> 10;
    const int base = tid * C;
    int s = 0;
    for (int j = 0; j < C; ++j) { int idx = base + j; if (idx < N) s += hist[idx]; }
    part[tid] = s;
    __syncthreads();
    for (int d = 1; d < 1024; d <<= 1) {
        int u = (tid >= d) ? part[tid - d] : 0;
        __syncthreads();
        part[tid] += u;
        __syncthreads();
    }
    int run = part[tid] - s;
    for (int j = 0; j < C; ++j) {
        int idx = base + j;
        if (idx < N) { off[idx] = run; cnt[idx] = run; run += hist[idx]; }
    }
    if (tid == 1023) off[N] = part[1023];
}

// ---------------- fused scatter + stream permute (sorted order) ----------------
__global__ void k_scatter(const int* __restrict__ eidx, const float* __restrict__ rshs,
                          const float* __restrict__ ea_g, int* __restrict__ cnt,
                          int* __restrict__ nsort, int* __restrict__ send_p,
                          float4* __restrict__ rshs_p, bf16_t* __restrict__ ea32, int E)
{
    for (int e = blockIdx.x * blockDim.x + threadIdx.x; e < E; e += gridDim.x * blockDim.x) {
        int n = eidx[e];
        int pos = atomicAdd(&cnt[n], 1);
        nsort[pos] = n;
        send_p[pos] = eidx[E + e];
        rshs_p[pos] = *(const float4*)(rshs + (size_t)e*4);
        const float* src = ea_g + (size_t)e*20;
        bf16_t tmp[32];
        #pragma unroll
        for (int j = 0; j < 20; ++j) tmp[j] = (bf16_t)src[j];
        #pragma unroll
        for (int j = 20; j < 32; ++j) tmp[j] = (bf16_t)(0.f);
        bf16_t* dst = ea32 + (size_t)pos*32;
        #pragma unroll
        for (int q = 0; q < 4; ++q)
            *((v8bf*)dst + q) = *((const v8bf*)tmp + q);
    }
}

// ---------------- node prep ----------------
__global__ __launch_bounds__(256) void k_nodeprep(
    const float* __restrict__ nf,
    const float* __restrict__ w0s, const float* __restrict__ b0s, const float* __restrict__ w0v,
    const float* __restrict__ w1s, const float* __restrict__ b1s, const float* __restrict__ w1v,
    bf16_t* __restrict__ ps_bf, bf16_t* __restrict__ pv_bf,
    bf16_t* __restrict__ xs_bf, bf16_t* __restrict__ xv4, int N)
{
    __shared__ float s_in[16][128];
    __shared__ float vt[3][64][16];   // [m][c][node]
    const int tid = threadIdx.x;
    const int nb = blockIdx.x * 16;
    const size_t N64 = (size_t)N * 64;

    for (int idx = tid; idx < 16*320; idx += 256) {
        int n = idx / 320, c = idx % 320;
        int gn = nb + n; if (gn >= N) gn = N - 1;
        float v = nf[(size_t)gn*320 + c];
        if (c < 128) s_in[n][c] = v;
        else { int q = c - 128; vt[q % 3][q / 3][n] = v; }
    }
    __syncthreads();

    {
        const int col = tid & 127, g = tid >> 7;
        float acc[8];
        #pragma unroll
        for (int j = 0; j < 8; ++j) acc[j] = 0.f;
        for (int c4 = 0; c4 < 128; c4 += 4) {
            float wa = w0s[(c4+0)*128 + col];
            float wb = w0s[(c4+1)*128 + col];
            float wc = w0s[(c4+2)*128 + col];
            float wd = w0s[(c4+3)*128 + col];
            #pragma unroll
            for (int j = 0; j < 8; ++j) {
                float4 sv = *(const float4*)&s_in[g*8+j][c4];
                acc[j] += sv.x*wa + sv.y*wb + sv.z*wc + sv.w*wd;
            }
        }
        float b = b0s[col];
        #pragma unroll
        for (int j = 0; j < 8; ++j) {
            int gn = nb + g*8 + j;
            if (gn < N) ps_bf[(size_t)gn*128 + col] = (bf16_t)(acc[j] + b);
        }
    }
    if (tid < 192) {
        const int d = tid & 63, m = tid >> 6;
        float acc[16];
        #pragma unroll
        for (int j = 0; j < 16; ++j) acc[j] = 0.f;
        for (int c = 0; c < 64; ++c) {
            float w = w0v[c*64 + d];
            float4 a0 = *(const float4*)&vt[m][c][0];
            float4 a1 = *(const float4*)&vt[m][c][4];
            float4 a2 = *(const float4*)&vt[m][c][8];
            float4 a3 = *(const float4*)&vt[m][c][12];
            acc[0]+=a0.x*w; acc[1]+=a0.y*w; acc[2]+=a0.z*w; acc[3]+=a0.w*w;
            acc[4]+=a1.x*w; acc[5]+=a1.y*w; acc[6]+=a1.z*w; acc[7]+=a1.w*w;
            acc[8]+=a2.x*w; acc[9]+=a2.y*w; acc[10]+=a2.z*w; acc[11]+=a2.w*w;
            acc[12]+=a3.x*w; acc[13]+=a3.y*w; acc[14]+=a3.z*w; acc[15]+=a3.w*w;
        }
        #pragma unroll
        for (int j = 0; j < 16; ++j) {
            int gn = nb + j;
            if (gn < N) pv_bf[(size_t)m*N64 + (size_t)gn*64 + d] = (bf16_t)acc[j];
        }
    }
    __syncthreads();

    for (int idx = tid; idx < 2048; idx += 256) {
        int n = idx >> 7, c = idx & 127;
        s_in[n][c] = siluf(s_in[n][c]);
    }
    for (int idx = tid; idx < 1024; idx += 256) {
        int n = idx & 15, cc = idx >> 4;
        float v0 = vt[0][cc][n], v1 = vt[1][cc][n], v2 = vt[2][cc][n];
        float nn = sqrtf(v0*v0 + v1*v1 + v2*v2 + 1e-10f);
        float sc = 1.f / (1.f + __expf(-nn));
        vt[0][cc][n] = v0*sc; vt[1][cc][n] = v1*sc; vt[2][cc][n] = v2*sc;
    }
    __syncthreads();

    {
        const int col = tid & 127, g = tid >> 7;
        float acc[8];
        #pragma unroll
        for (int j = 0; j < 8; ++j) acc[j] = 0.f;
        for (int c4 = 0; c4 < 128; c4 += 4) {
            float wa = w1s[(c4+0)*128 + col];
            float wb = w1s[(c4+1)*128 + col];
            float wc = w1s[(c4+2)*128 + col];
            float wd = w1s[(c4+3)*128 + col];
            #pragma unroll
            for (int j = 0; j < 8; ++j) {
                float4 sv = *(const float4*)&s_in[g*8+j][c4];
                acc[j] += sv.x*wa + sv.y*wb + sv.z*wc + sv.w*wd;
            }
        }
        float b = b1s[col];
        #pragma unroll
        for (int j = 0; j < 8; ++j) {
            int gn = nb + g*8 + j;
            if (gn < N) xs_bf[(size_t)gn*128 + col] = (bf16_t)(acc[j] + b);
        }
    }
    if (tid < 192) {
        const int d = tid & 63, m = tid >> 6;
        float acc[16];
        #pragma unroll
        for (int j = 0; j < 16; ++j) acc[j] = 0.f;
        for (int c = 0; c < 64; ++c) {
            float w = w1v[c*64 + d];
            float4 a0 = *(const float4*)&vt[m][c][0];
            float4 a1 = *(const float4*)&vt[m][c][4];
            float4 a2 = *(const float4*)&vt[m][c][8];
            float4 a3 = *(const float4*)&vt[m][c][12];
            acc[0]+=a0.x*w; acc[1]+=a0.y*w; acc[2]+=a0.z*w; acc[3]+=a0.w*w;
            acc[4]+=a1.x*w; acc[5]+=a1.y*w; acc[6]+=a1.z*w; acc[7]+=a1.w*w;
            acc[8]+=a2.x*w; acc[9]+=a2.y*w; acc[10]+=a2.z*w; acc[11]+=a2.w*w;
            acc[12]+=a3.x*w; acc[13]+=a3.y*w; acc[14]+=a3.z*w; acc[15]+=a3.w*w;
        }
        // xv4 layout: [node][64][4] (4th slot unused)
        #pragma unroll
        for (int j = 0; j < 16; ++j) {
            int gn = nb + j;
            if (gn < N) xv4[(size_t)gn*256 + d*4 + m] = (bf16_t)acc[j];
        }
    }
}

// ---------------- edge MLP: 32-edge tile, 4 waves, 32x32x16 MFMA, XCD-chunked tiles ----------------
__global__ __launch_bounds__(256) void k_edge2(
    const int* __restrict__ nsort, const int* __restrict__ send_p,
    const bf16_t* __restrict__ ea32,
    const bf16_t* __restrict__ ps_bf, const bf16_t* __restrict__ pv_bf,
    const bf16_t* __restrict__ p1, const bf16_t* __restrict__ p2,
    const bf16_t* __restrict__ p3, const bf16_t* __restrict__ p4,
    const float* __restrict__ es_b1, const float* __restrict__ es_b2,
    const float* __restrict__ er_b1, const float* __restrict__ er_b2,
    bf16_t* __restrict__ w_bf, int N, int E)
{
    __shared__ __align__(16) bf16_t s0h[32*S0STR];   // s0 tile; reused for h1/h2
    __shared__ int   recv_l[32], send_l[32];

    const int tid  = threadIdx.x;
    const int lane = tid & 63;
    const int wid  = tid >> 6;     // 0..3 = this wave's 32-col group
    // XCD-chunked swizzle: consecutive tiles (sharing sorted recv nodes) stay on one XCD
    int bid = blockIdx.x, nwg = gridDim.x, tile;
    if ((nwg & 7) == 0) { int cpx = nwg >> 3; tile = (bid & 7) * cpx + (bid >> 3); }
    else tile = bid;
    const int e0 = tile * 32;
    const size_t N64 = (size_t)N * 64;

    if (tid < 32) {
        int i = e0 + tid; if (i >= E) i = E - 1;
        recv_l[tid] = nsort[i];
        send_l[tid] = send_p[i];
    }
    __syncthreads();

    #pragma unroll
    for (int rr = 0; rr < 8; ++rr) {
        int r = wid*8 + rr;
        int nr = recv_l[r], nsd = send_l[r];
        if (lane < 32) {
            *(uint2*)&s0h[r*S0STR + lane*4] = *(const uint2*)(ps_bf + (size_t)nr*NSC + lane*4);
        } else {
            int l2 = lane - 32;
            *(uint2*)&s0h[r*S0STR + 128 + l2*4] = *(const uint2*)(ps_bf + (size_t)nsd*NSC + l2*4);
        }
        float d = 0.f;
        #pragma unroll
        for (int m = 0; m < 3; ++m)
            d += (float)pv_bf[m*N64 + (size_t)nr*64 + lane] * (float)pv_bf[m*N64 + (size_t)nsd*64 + lane];
        s0h[r*S0STR + 256 + lane] = (bf16_t)d;
    }
    __syncthreads();

    const int lc = lane & 31;      // A row / B col within 32
    const int kh = lane >> 5;      // k half (0/1) -> k offset kh*8
    bf16_t* h1 = s0h;              // 32 x HSTR
    bf16_t* h2 = s0h + 32*HSTR;
    const int col1 = wid*32 + lc;

    v16f acc;

    // ---- GEMM1 (K=320, 20 chunks) ----
    #pragma unroll
    for (int j = 0; j < 16; ++j) acc[j] = 0.f;
    {
        const bf16_t* aB = &s0h[lc*S0STR + kh*8];
        #pragma unroll
        for (int kc = 0; kc < 20; ++kc) {
            v8bf a = *(const v8bf*)(aB + kc*16);
            v8bf b = *(const v8bf*)(p1 + (size_t)((kc<<2) + wid)*512 + lane*8);
            acc = __builtin_amdgcn_mfma_f32_32x32x16_bf16(a, b, acc, 0, 0, 0);
        }
    }
    __syncthreads();   // all s0h reads done; safe to overwrite with h1/h2

    {
        const float be = es_b1[col1];
        #pragma unroll
        for (int reg = 0; reg < 16; ++reg) {
            int row = (reg & 3) + 8*(reg >> 2) + 4*kh;
            h1[row*HSTR + col1] = (bf16_t)siluf(acc[reg] + be);
        }
    }

    // ---- GEMM3 (K=32, 2 chunks), reuse acc ----
    #pragma unroll
    for (int j = 0; j < 16; ++j) acc[j] = 0.f;
    #pragma unroll
    for (int kc = 0; kc < 2; ++kc) {
        v8bf a = *(const v8bf*)(ea32 + (size_t)(e0 + lc)*32 + kc*16 + kh*8);
        v8bf b = *(const v8bf*)(p3 + (size_t)((kc<<2) + wid)*512 + lane*8);
        acc = __builtin_amdgcn_mfma_f32_32x32x16_bf16(a, b, acc, 0, 0, 0);
    }
    {
        const float br = er_b1[col1];
        #pragma unroll
        for (int reg = 0; reg < 16; ++reg) {
            int row = (reg & 3) + 8*(reg >> 2) + 4*kh;
            h2[row*HSTR + col1] = (bf16_t)siluf(acc[reg] + br);
        }
    }
    __syncthreads();

    // ---- GEMM2/4 (K=128, 8 chunks), 3 column-chunk passes; es staged to bf16, then er ----
    #pragma unroll
    for (int ch = 0; ch < 3; ++ch) {
        #pragma unroll
        for (int j = 0; j < 16; ++j) acc[j] = 0.f;
        #pragma unroll
        for (int kc = 0; kc < 8; ++kc) {
            v8bf a1 = *(const v8bf*)&h1[lc*HSTR + kc*16 + kh*8];
            v8bf b1 = *(const v8bf*)(p2 + (size_t)(((ch*8 + kc)<<2) + wid)*512 + lane*8);
            acc = __builtin_amdgcn_mfma_f32_32x32x16_bf16(a1, b1, acc, 0, 0, 0);
        }
        const int col = ch*128 + wid*32 + lc;
        const float be = es_b2[col];
        bf16_t hes[16];
        #pragma unroll
        for (int reg = 0; reg < 16; ++reg) hes[reg] = (bf16_t)(acc[reg] + be);

        #pragma unroll
        for (int j = 0; j < 16; ++j) acc[j] = 0.f;
        #pragma unroll
        for (int kc = 0; kc < 8; ++kc) {
            v8bf a2 = *(const v8bf*)&h2[lc*HSTR + kc*16 + kh*8];
            v8bf b2 = *(const v8bf*)(p4 + (size_t)(((ch*8 + kc)<<2) + wid)*512 + lane*8);
            acc = __builtin_amdgcn_mfma_f32_32x32x16_bf16(a2, b2, acc, 0, 0, 0);
        }
        const float br = er_b2[col];
        // interleaved index: (w1[c],w2[c]) at c*2, c*2+1; (w3[u],w4[u]) at 256+u*2, 257+u*2
        int idx;
        if (ch == 0)      idx = col*2;
        else if (ch == 1) idx = (col - 128)*2 + 1;
        else { int q = col - 256; idx = (q < 64) ? 256 + q*2 : 256 + (q - 64)*2 + 1; }
        #pragma unroll
        for (int reg = 0; reg < 16; ++reg) {
            int row = (reg & 3) + 8*(reg >> 2) + 4*kh;
            int i = e0 + row;
            if (i < E) w_bf[(size_t)i*WNUM + idx] = (bf16_t)((float)hes[reg] * (acc[reg] + br));
        }
    }
}

// ---------------- per-node gather, 8 nodes/block, 2 groups x 192 thr (batched lin2) ----------------
__global__ __launch_bounds__(384) void k_gather(
    const int* __restrict__ off, const int* __restrict__ send_p,
    const float4* __restrict__ rshs_p,
    const bf16_t* __restrict__ xs_bf, const bf16_t* __restrict__ xv4,
    const bf16_t* __restrict__ w_bf,
    const float* __restrict__ nf,
    const float* __restrict__ w2s, const float* __restrict__ b2s, const float* __restrict__ w2v,
    const float* __restrict__ ln_gs, const float* __restrict__ ln_bs, const float* __restrict__ ln_gv,
    float* __restrict__ out, int N, int E)
{
    __shared__ float accS_l[GNB][192];
    __shared__ float accV_l[GNB][576];
    __shared__ float os_l[GNB][128];
    __shared__ float ov_l[GNB][192];
    __shared__ float stats[GNB][3];
    const int tid = threadIdx.x;
    const int grp = tid / 192;     // 0..1 — two independent node pipelines
    const int lt  = tid - grp*192;
    const int nb = blockIdx.x * GNB;

    for (int nn = grp; nn < GNB; nn += 2) {
        int node = nb + nn;
        int i0 = 0, i1 = 0;
        if (node < N) { i0 = off[node]; i1 = off[node+1]; }
        float a0 = 0.f, a1 = 0.f, a2 = 0.f, a3 = 0.f;
        float b0 = 0.f, b1 = 0.f, b2 = 0.f, b3 = 0.f;
        if (lt < 128) {
            const int c = lt;
            int i = i0;
            for (; i + 2 <= i1; i += 2) {
                int nsdA = send_p[i],   nsdB = send_p[i+1];
                float4 yA = rshs_p[i],  yB = rshs_p[i+1];
                v2bf wA = *(const v2bf*)(w_bf + (size_t)i*WNUM + c*2);
                v2bf wB = *(const v2bf*)(w_bf + (size_t)(i+1)*WNUM + c*2);
                float xsA = (float)xs_bf[(size_t)nsdA*NSC + c];
                float xsB = (float)xs_bf[(size_t)nsdB*NSC + c];
                a0 += xsA * yA.x * (float)wA[0];
                b0 += xsB * yB.x * (float)wB[0];
                float xwA = xsA * (float)wA[1], xwB = xsB * (float)wB[1];
                a1 += xwA * yA.y; a2 += xwA * yA.z; a3 += xwA * yA.w;
                b1 += xwB * yB.y; b2 += xwB * yB.z; b3 += xwB * yB.w;
            }
            if (i < i1) {
                int nsd = send_p[i];
                float4 y = rshs_p[i];
                v2bf w = *(const v2bf*)(w_bf + (size_t)i*WNUM + c*2);
                float xs = (float)xs_bf[(size_t)nsd*NSC + c];
                a0 += xs * y.x * (float)w[0];
                float xw = xs * (float)w[1];
                a1 += xw * y.y; a2 += xw * y.z; a3 += xw * y.w;
            }
            a0 += b0; a1 += b1; a2 += b2; a3 += b3;
            accS_l[nn][c] = a0;
            accV_l[nn][c*3+0] = a1; accV_l[nn][c*3+1] = a2; accV_l[nn][c*3+2] = a3;
        } else {
            const int u = lt - 128;
            int i = i0;
            for (; i + 2 <= i1; i += 2) {
                int nsdA = send_p[i],   nsdB = send_p[i+1];
                float4 yA = rshs_p[i],  yB = rshs_p[i+1];
                v2bf wA = *(const v2bf*)(w_bf + (size_t)i*WNUM + 256 + u*2);
                v2bf wB = *(const v2bf*)(w_bf + (size_t)(i+1)*WNUM + 256 + u*2);
                v4bf xvA = *(const v4bf*)(xv4 + (size_t)nsdA*256 + u*4);
                v4bf xvB = *(const v4bf*)(xv4 + (size_t)nsdB*256 + u*4);
                float vA0 = (float)xvA[0], vA1 = (float)xvA[1], vA2 = (float)xvA[2];
                float vB0 = (float)xvB[0], vB1 = (float)xvB[1], vB2 = (float)xvB[2];
                a0 += (vA0*yA.y + vA1*yA.z + vA2*yA.w) * (float)wA[1] * 0.57735026918962576f;
                b0 += (vB0*yB.y + vB1*yB.z + vB2*yB.w) * (float)wB[1] * 0.57735026918962576f;
                float sA = yA.x * (float)wA[0], sB = yB.x * (float)wB[0];
                a1 += vA0*sA; a2 += vA1*sA; a3 += vA2*sA;
                b1 += vB0*sB; b2 += vB1*sB; b3 += vB2*sB;
            }
            if (i < i1) {
                int nsd = send_p[i];
                float4 y = rshs_p[i];
                v2bf w = *(const v2bf*)(w_bf + (size_t)i*WNUM + 256 + u*2);
                v4bf xv = *(const v4bf*)(xv4 + (size_t)nsd*256 + u*4);
                float v0 = (float)xv[0], v1 = (float)xv[1], v2 = (float)xv[2];
                a0 += (v0*y.y + v1*y.z + v2*y.w) * (float)w[1] * 0.57735026918962576f;
                float s = y.x * (float)w[0];
                a1 += v0*s; a2 += v1*s; a3 += v2*s;
            }
            a0 += b0; a1 += b1; a2 += b2; a3 += b3;
            accS_l[nn][128+u] = a0;
            accV_l[nn][(128+u)*3+0] = a1; accV_l[nn][(128+u)*3+1] = a2; accV_l[nn][(128+u)*3+2] = a3;
        }
    }
    __syncthreads();

    // lin2 batched over GNB nodes: each weight element loaded once per block
    for (int o = tid; o < 320; o += 384) {
        if (o < 128) {
            float acc[GNB];
            #pragma unroll
            for (int nn = 0; nn < GNB; ++nn) acc[nn] = 0.f;
            for (int c = 0; c < 192; ++c) {
                float w = w2s[c*128 + o];
                #pragma unroll
                for (int nn = 0; nn < GNB; ++nn) acc[nn] += accS_l[nn][c] * w;
            }
            float b = b2s[o];
            #pragma unroll
            for (int nn = 0; nn < GNB; ++nn) os_l[nn][o] = acc[nn] + b;
        } else {
            int q = o - 128;
            int m = q % 3, d = q / 3;
            float acc[GNB];
            #pragma unroll
            for (int nn = 0; nn < GNB; ++nn) acc[nn] = 0.f;
            for (int c = 0; c < 192; ++c) {
                float w = w2v[c*64 + d];
                #pragma unroll
                for (int nn = 0; nn < GNB; ++nn) acc[nn] += accV_l[nn][c*3 + m] * w;
            }
            #pragma unroll
            for (int nn = 0; nn < GNB; ++nn) ov_l[nn][q] = acc[nn];
        }
    }
    __syncthreads();

    // norms: 6 waves cover GNB nodes
    {
        const int lane = tid & 63, wv = tid >> 6;
        for (int nn = wv; nn < GNB; nn += 6) {
            float x0 = os_l[nn][lane], x1 = os_l[nn][lane + 64];
            float s = x0 + x1;
            #pragma unroll
            for (int o = 32; o > 0; o >>= 1) s += __shfl_xor(s, o);
            float mu = s * (1.f/128.f);
            float d0 = x0 - mu, d1 = x1 - mu;
            float q = d0*d0 + d1*d1;
            #pragma unroll
            for (int o = 32; o > 0; o >>= 1) q += __shfl_xor(q, o);
            float var = q * (1.f/128.f);
            float v0 = ov_l[nn][lane], v1 = ov_l[nn][lane + 64], v2 = ov_l[nn][lane + 128];
            float q2 = v0*v0 + v1*v1 + v2*v2;
            #pragma unroll
            for (int o = 32; o > 0; o >>= 1) q2 += __shfl_xor(q2, o);
            float n2 = q2 * (1.f/64.f);
            if (lane == 0) {
                stats[nn][0] = mu;
                stats[nn][1] = rsqrtf(var + 1e-5f);
                stats[nn][2] = rsqrtf(n2 + 1e-5f);
            }
        }
    }
    __syncthreads();

    for (int i = tid; i < GNB*DDIM; i += 384) {
        int nn = i / DDIM, j = i % DDIM;
        int node = nb + nn;
        if (node >= N) continue;
        const float mu = stats[nn][0], rstd = stats[nn][1], rn2 = stats[nn][2];
        const size_t base = (size_t)node * DDIM;
        if (j < 128) {
            out[base + j] = nf[base + j] + (os_l[nn][j] - mu) * rstd * ln_gs[j] + ln_bs[j];
        } else {
            int o = j - 128;
            int d = o / 3;
            out[base + j] = nf[base + j] + ov_l[nn][o] * rn2 * ln_gv[128 + d];
        }
    }
}

static inline size_t align64(size_t x) { return (x + 63) & ~(size_t)63; }

extern "C" void kernel_launch(void* const* d_in, const int* in_sizes, int n_in,
                              void* d_out, int out_size, void* d_ws, size_t ws_size,
                              hipStream_t stream)
{
    const float* nf    = (const float*)d_in[0];
    const float* ea_g  = (const float*)d_in[1];
    const float* rshs  = (const float*)d_in[2];
    const int*   eidx  = (const int*)  d_in[3];
    const float* w0s   = (const float*)d_in[4];
    const float* b0s   = (const float*)d_in[5];
    const float* w0v   = (const float*)d_in[6];
    const float* w1s   = (const float*)d_in[7];
    const float* b1s   = (const float*)d_in[8];
    const float* w1v   = (const float*)d_in[9];
    const float* w2s   = (const float*)d_in[10];
    const float* b2s   = (const float*)d_in[11];
    const float* w2v   = (const float*)d_in[12];
    const float* esw1  = (const float*)d_in[13];
    const float* esb1  = (const float*)d_in[14];
    const float* esw2  = (const float*)d_in[15];
    const float* esb2  = (const float*)d_in[16];
    const float* erw1  = (const float*)d_in[17];
    const float* erb1  = (const float*)d_in[18];
    const float* erw2  = (const float*)d_in[19];
    const float* erb2  = (const float*)d_in[20];
    const float* ln_gs = (const float*)d_in[21];
    const float* ln_bs = (const float*)d_in[22];
    const float* ln_gv = (const float*)d_in[23];

    const int N = in_sizes[0] / DDIM;
    const int E = in_sizes[3] / 2;

    char* p = (char*)d_ws;
    size_t o = 0;
    int* hist = (int*)(p + o);  o = align64(o + (size_t)N * 4);
    int* off  = (int*)(p + o);  o = align64(o + (size_t)(N + 1) * 4);
    int* cnt  = (int*)(p + o);  o = align64(o + (size_t)N * 4);
    int* nsort= (int*)(p + o);  o = align64(o + (size_t)E * 4);
    int* send_p = (int*)(p + o); o = align64(o + (size_t)E * 4);
    float4* rshs_p = (float4*)(p + o); o = align64(o + (size_t)E * 16);
    bf16_t* ea32 = (bf16_t*)(p + o); o = align64(o + (size_t)(E + 64) * 32 * 2);
    bf16_t* ps_bf = (bf16_t*)(p + o); o = align64(o + (size_t)N * 128 * 2);
    bf16_t* pv_bf = (bf16_t*)(p + o); o = align64(o + (size_t)N * 192 * 2);
    bf16_t* xs_bf = (bf16_t*)(p + o); o = align64(o + (size_t)N * 128 * 2);
    bf16_t* xv4  = (bf16_t*)(p + o); o = align64(o + (size_t)N * 256 * 2);
    bf16_t* p1 = (bf16_t*)(p + o); o = align64(o + (size_t)80 * 512 * 2);
    bf16_t* p2 = (bf16_t*)(p + o); o = align64(o + (size_t)96 * 512 * 2);
    bf16_t* p3 = (bf16_t*)(p + o); o = align64(o + (size_t)8  * 512 * 2);
    bf16_t* p4 = (bf16_t*)(p + o); o = align64(o + (size_t)96 * 512 * 2);
    bf16_t* w_bf  = (bf16_t*)(p + o); o = align64(o + (size_t)E * WNUM * 2);

    hipMemsetAsync(hist, 0, (size_t)N * 4, stream);
    k_wconv<<<512, 256, 0, stream>>>(esw1, esw2, erw1, erw2, p1, p2, p3, p4, eidx, hist, E);
    k_nodeprep<<<(N + 15)/16, 256, 0, stream>>>(nf, w0s, b0s, w0v, w1s, b1s, w1v,
                                                ps_bf, pv_bf, xs_bf, xv4, N);
    k_scan<<<1, 1024, 0, stream>>>(hist, off, cnt, N);
    k_scatter<<<512, 256, 0, stream>>>(eidx, rshs, ea_g, cnt,
                                       nsort, send_p, rshs_p, ea32, E);
    k_edge2<<<(E + 31)/32, 256, 0, stream>>>(nsort, send_p, ea32, ps_bf, pv_bf,
                                             p1, p2, p3, p4,
                                             esb1, esb2, erb1, erb2, w_bf, N, E);
    k_gather<<<(N + GNB - 1)/GNB, 384, 0, stream>>>(off, send_p, rshs_p, xs_bf, xv4, w_bf,
                                                    nf, w2s, b2s, w2v, ln_gs, ln_bs, ln_gv,
                                                    (float*)d_out, N, E);
}

// Round 15
// 268.564 us; speedup vs baseline: 1.1319x; 1.1319x over previous
//
#include <hip/hip_runtime.h>
#include <hip/hip_bf16.h>

typedef __bf16 bf16_t;
typedef __bf16 v8bf __attribute__((ext_vector_type(8)));
typedef __bf16 v2bf __attribute__((ext_vector_type(2)));
typedef __bf16 v4bf __attribute__((ext_vector_type(4)));
typedef float  v16f __attribute__((ext_vector_type(16)));

#define NSC   128   // scalar channels
#define NVC   64    // vector channels
#define DDIM  320   // NSC + 3*NVC
#define HIDN  128
#define WNUM  384
#define S0STR 328   // s0 tile stride (656B rows, 16B-aligned)
#define HSTR  136   // h1/h2 stride (272B rows, 16B-aligned)
#define GNB   4     // nodes per gather block

__device__ __forceinline__ float siluf(float x) { return x / (1.f + __expf(-x)); }

// ---------------- weight conversion (32x32x16 fragments) + recv histogram ----------------
// B-fragment (32x32x16): lane l holds col n = nt*32 + (l&31), k = kbase + (l>>5)*8 .. +8.
// p1: [kc 0..19][nt 0..3] ; p3: [kc 0..1][nt] ; p2/p4: [ch][kc 0..7][nt]
__global__ void k_wconv(const float* __restrict__ esw1, const float* __restrict__ esw2,
                        const float* __restrict__ erw1, const float* __restrict__ erw2,
                        bf16_t* __restrict__ p1, bf16_t* __restrict__ p2,
                        bf16_t* __restrict__ p3, bf16_t* __restrict__ p4,
                        const int* __restrict__ eidx, int* __restrict__ hist, int E)
{
    const int gid = blockIdx.x * blockDim.x + threadIdx.x;
    const int stride = gridDim.x * blockDim.x;
    for (int i = gid; i < 80*512; i += stride) {
        int frag = i >> 9, q = i & 511, lane = q >> 3, j = q & 7;
        int kc = frag >> 2, nt = frag & 3;
        int n = nt*32 + (lane & 31), k = kc*16 + (lane >> 5)*8 + j;
        p1[i] = (bf16_t)esw1[k*128 + n];
    }
    for (int i = gid; i < 8*512; i += stride) {
        int frag = i >> 9, q = i & 511, lane = q >> 3, j = q & 7;
        int kc = frag >> 2, nt = frag & 3;
        int n = nt*32 + (lane & 31), k = kc*16 + (lane >> 5)*8 + j;
        p3[i] = (k < 20) ? (bf16_t)erw1[k*128 + n] : (bf16_t)(0.f);
    }
    for (int i = gid; i < 96*512; i += stride) {
        int frag = i >> 9, q = i & 511, lane = q >> 3, j = q & 7;
        int ch = frag >> 5, kc = (frag >> 2) & 7, nt = frag & 3;
        int n = ch*128 + nt*32 + (lane & 31), k = kc*16 + (lane >> 5)*8 + j;
        p2[i] = (bf16_t)esw2[k*384 + n];
        p4[i] = (bf16_t)erw2[k*384 + n];
    }
    for (int e = gid; e < E; e += stride)
        atomicAdd(&hist[eidx[e]], 1);
}

__global__ __launch_bounds__(1024) void k_scan(const int* __restrict__ hist,
                                               int* __restrict__ off, int* __restrict__ cnt, int N)
{
    __shared__ int part[1024];
    const int tid = threadIdx.x;
    const int C = (N + 1023) >> 10;
    const int base = tid * C;
    int s = 0;
    for (int j = 0; j < C; ++j) { int idx = base + j; if (idx < N) s += hist[idx]; }
    part[tid] = s;
    __syncthreads();
    for (int d = 1; d < 1024; d <<= 1) {
        int u = (tid >= d) ? part[tid - d] : 0;
        __syncthreads();
        part[tid] += u;
        __syncthreads();
    }
    int run = part[tid] - s;
    for (int j = 0; j < C; ++j) {
        int idx = base + j;
        if (idx < N) { off[idx] = run; cnt[idx] = run; run += hist[idx]; }
    }
    if (tid == 1023) off[N] = part[1023];
}

// ---------------- fused scatter + stream permute (sorted order) ----------------
__global__ void k_scatter(const int* __restrict__ eidx, const float* __restrict__ rshs,
                          const float* __restrict__ ea_g, int* __restrict__ cnt,
                          int* __restrict__ nsort, int* __restrict__ send_p,
                          float4* __restrict__ rshs_p, bf16_t* __restrict__ ea32, int E)
{
    for (int e = blockIdx.x * blockDim.x + threadIdx.x; e < E; e += gridDim.x * blockDim.x) {
        int n = eidx[e];
        int pos = atomicAdd(&cnt[n], 1);
        nsort[pos] = n;
        send_p[pos] = eidx[E + e];
        rshs_p[pos] = *(const float4*)(rshs + (size_t)e*4);
        const float* src = ea_g + (size_t)e*20;
        bf16_t tmp[32];
        #pragma unroll
        for (int j = 0; j < 20; ++j) tmp[j] = (bf16_t)src[j];
        #pragma unroll
        for (int j = 20; j < 32; ++j) tmp[j] = (bf16_t)(0.f);
        bf16_t* dst = ea32 + (size_t)pos*32;
        #pragma unroll
        for (int q = 0; q < 4; ++q)
            *((v8bf*)dst + q) = *((const v8bf*)tmp + q);
    }
}

// ---------------- node prep ----------------
__global__ __launch_bounds__(256) void k_nodeprep(
    const float* __restrict__ nf,
    const float* __restrict__ w0s, const float* __restrict__ b0s, const float* __restrict__ w0v,
    const float* __restrict__ w1s, const float* __restrict__ b1s, const float* __restrict__ w1v,
    bf16_t* __restrict__ ps_bf, bf16_t* __restrict__ pv_bf,
    bf16_t* __restrict__ xs_bf, bf16_t* __restrict__ xv4, int N)
{
    __shared__ float s_in[16][128];
    __shared__ float vt[3][64][16];   // [m][c][node]
    const int tid = threadIdx.x;
    const int nb = blockIdx.x * 16;
    const size_t N64 = (size_t)N * 64;

    for (int idx = tid; idx < 16*320; idx += 256) {
        int n = idx / 320, c = idx % 320;
        int gn = nb + n; if (gn >= N) gn = N - 1;
        float v = nf[(size_t)gn*320 + c];
        if (c < 128) s_in[n][c] = v;
        else { int q = c - 128; vt[q % 3][q / 3][n] = v; }
    }
    __syncthreads();

    {
        const int col = tid & 127, g = tid >> 7;
        float acc[8];
        #pragma unroll
        for (int j = 0; j < 8; ++j) acc[j] = 0.f;
        for (int c4 = 0; c4 < 128; c4 += 4) {
            float wa = w0s[(c4+0)*128 + col];
            float wb = w0s[(c4+1)*128 + col];
            float wc = w0s[(c4+2)*128 + col];
            float wd = w0s[(c4+3)*128 + col];
            #pragma unroll
            for (int j = 0; j < 8; ++j) {
                float4 sv = *(const float4*)&s_in[g*8+j][c4];
                acc[j] += sv.x*wa + sv.y*wb + sv.z*wc + sv.w*wd;
            }
        }
        float b = b0s[col];
        #pragma unroll
        for (int j = 0; j < 8; ++j) {
            int gn = nb + g*8 + j;
            if (gn < N) ps_bf[(size_t)gn*128 + col] = (bf16_t)(acc[j] + b);
        }
    }
    if (tid < 192) {
        const int d = tid & 63, m = tid >> 6;
        float acc[16];
        #pragma unroll
        for (int j = 0; j < 16; ++j) acc[j] = 0.f;
        for (int c = 0; c < 64; ++c) {
            float w = w0v[c*64 + d];
            float4 a0 = *(const float4*)&vt[m][c][0];
            float4 a1 = *(const float4*)&vt[m][c][4];
            float4 a2 = *(const float4*)&vt[m][c][8];
            float4 a3 = *(const float4*)&vt[m][c][12];
            acc[0]+=a0.x*w; acc[1]+=a0.y*w; acc[2]+=a0.z*w; acc[3]+=a0.w*w;
            acc[4]+=a1.x*w; acc[5]+=a1.y*w; acc[6]+=a1.z*w; acc[7]+=a1.w*w;
            acc[8]+=a2.x*w; acc[9]+=a2.y*w; acc[10]+=a2.z*w; acc[11]+=a2.w*w;
            acc[12]+=a3.x*w; acc[13]+=a3.y*w; acc[14]+=a3.z*w; acc[15]+=a3.w*w;
        }
        #pragma unroll
        for (int j = 0; j < 16; ++j) {
            int gn = nb + j;
            if (gn < N) pv_bf[(size_t)m*N64 + (size_t)gn*64 + d] = (bf16_t)acc[j];
        }
    }
    __syncthreads();

    for (int idx = tid; idx < 2048; idx += 256) {
        int n = idx >> 7, c = idx & 127;
        s_in[n][c] = siluf(s_in[n][c]);
    }
    for (int idx = tid; idx < 1024; idx += 256) {
        int n = idx & 15, cc = idx >> 4;
        float v0 = vt[0][cc][n], v1 = vt[1][cc][n], v2 = vt[2][cc][n];
        float nn = sqrtf(v0*v0 + v1*v1 + v2*v2 + 1e-10f);
        float sc = 1.f / (1.f + __expf(-nn));
        vt[0][cc][n] = v0*sc; vt[1][cc][n] = v1*sc; vt[2][cc][n] = v2*sc;
    }
    __syncthreads();

    {
        const int col = tid & 127, g = tid >> 7;
        float acc[8];
        #pragma unroll
        for (int j = 0; j < 8; ++j) acc[j] = 0.f;
        for (int c4 = 0; c4 < 128; c4 += 4) {
            float wa = w1s[(c4+0)*128 + col];
            float wb = w1s[(c4+1)*128 + col];
            float wc = w1s[(c4+2)*128 + col];
            float wd = w1s[(c4+3)*128 + col];
            #pragma unroll
            for (int j = 0; j < 8; ++j) {
                float4 sv = *(const float4*)&s_in[g*8+j][c4];
                acc[j] += sv.x*wa + sv.y*wb + sv.z*wc + sv.w*wd;
            }
        }
        float b = b1s[col];
        #pragma unroll
        for (int j = 0; j < 8; ++j) {
            int gn = nb + g*8 + j;
            if (gn < N) xs_bf[(size_t)gn*128 + col] = (bf16_t)(acc[j] + b);
        }
    }
    if (tid < 192) {
        const int d = tid & 63, m = tid >> 6;
        float acc[16];
        #pragma unroll
        for (int j = 0; j < 16; ++j) acc[j] = 0.f;
        for (int c = 0; c < 64; ++c) {
            float w = w1v[c*64 + d];
            float4 a0 = *(const float4*)&vt[m][c][0];
            float4 a1 = *(const float4*)&vt[m][c][4];
            float4 a2 = *(const float4*)&vt[m][c][8];
            float4 a3 = *(const float4*)&vt[m][c][12];
            acc[0]+=a0.x*w; acc[1]+=a0.y*w; acc[2]+=a0.z*w; acc[3]+=a0.w*w;
            acc[4]+=a1.x*w; acc[5]+=a1.y*w; acc[6]+=a1.z*w; acc[7]+=a1.w*w;
            acc[8]+=a2.x*w; acc[9]+=a2.y*w; acc[10]+=a2.z*w; acc[11]+=a2.w*w;
            acc[12]+=a3.x*w; acc[13]+=a3.y*w; acc[14]+=a3.z*w; acc[15]+=a3.w*w;
        }
        // xv4 layout: [node][64][4] (4th slot unused)
        #pragma unroll
        for (int j = 0; j < 16; ++j) {
            int gn = nb + j;
            if (gn < N) xv4[(size_t)gn*256 + d*4 + m] = (bf16_t)acc[j];
        }
    }
}

// ---------------- edge MLP: 32-edge tile, 4 waves, 32x32x16 MFMA, ONE live accumulator ----------------
__global__ __launch_bounds__(256) void k_edge2(
    const int* __restrict__ nsort, const int* __restrict__ send_p,
    const bf16_t* __restrict__ ea32,
    const bf16_t* __restrict__ ps_bf, const bf16_t* __restrict__ pv_bf,
    const bf16_t* __restrict__ p1, const bf16_t* __restrict__ p2,
    const bf16_t* __restrict__ p3, const bf16_t* __restrict__ p4,
    const float* __restrict__ es_b1, const float* __restrict__ es_b2,
    const float* __restrict__ er_b1, const float* __restrict__ er_b2,
    bf16_t* __restrict__ w_bf, int N, int E)
{
    __shared__ __align__(16) bf16_t s0h[32*S0STR];   // s0 tile; reused for h1/h2
    __shared__ int   recv_l[32], send_l[32];

    const int tid  = threadIdx.x;
    const int lane = tid & 63;
    const int wid  = tid >> 6;     // 0..3 = this wave's 32-col group
    const int e0   = blockIdx.x * 32;
    const size_t N64 = (size_t)N * 64;

    if (tid < 32) {
        int i = e0 + tid; if (i >= E) i = E - 1;
        recv_l[tid] = nsort[i];
        send_l[tid] = send_p[i];
    }
    __syncthreads();

    #pragma unroll
    for (int rr = 0; rr < 8; ++rr) {
        int r = wid*8 + rr;
        int nr = recv_l[r], nsd = send_l[r];
        if (lane < 32) {
            *(uint2*)&s0h[r*S0STR + lane*4] = *(const uint2*)(ps_bf + (size_t)nr*NSC + lane*4);
        } else {
            int l2 = lane - 32;
            *(uint2*)&s0h[r*S0STR + 128 + l2*4] = *(const uint2*)(ps_bf + (size_t)nsd*NSC + l2*4);
        }
        float d = 0.f;
        #pragma unroll
        for (int m = 0; m < 3; ++m)
            d += (float)pv_bf[m*N64 + (size_t)nr*64 + lane] * (float)pv_bf[m*N64 + (size_t)nsd*64 + lane];
        s0h[r*S0STR + 256 + lane] = (bf16_t)d;
    }
    __syncthreads();

    const int lc = lane & 31;      // A row / B col within 32
    const int kh = lane >> 5;      // k half (0/1) -> k offset kh*8
    bf16_t* h1 = s0h;              // 32 x HSTR
    bf16_t* h2 = s0h + 32*HSTR;
    const int col1 = wid*32 + lc;

    v16f acc;

    // ---- GEMM1 (K=320, 20 chunks) ----
    #pragma unroll
    for (int j = 0; j < 16; ++j) acc[j] = 0.f;
    {
        const bf16_t* aB = &s0h[lc*S0STR + kh*8];
        #pragma unroll
        for (int kc = 0; kc < 20; ++kc) {
            v8bf a = *(const v8bf*)(aB + kc*16);
            v8bf b = *(const v8bf*)(p1 + (size_t)((kc<<2) + wid)*512 + lane*8);
            acc = __builtin_amdgcn_mfma_f32_32x32x16_bf16(a, b, acc, 0, 0, 0);
        }
    }
    __syncthreads();   // all s0h reads done; safe to overwrite with h1/h2

    {
        const float be = es_b1[col1];
        #pragma unroll
        for (int reg = 0; reg < 16; ++reg) {
            int row = (reg & 3) + 8*(reg >> 2) + 4*kh;
            h1[row*HSTR + col1] = (bf16_t)siluf(acc[reg] + be);
        }
    }

    // ---- GEMM3 (K=32, 2 chunks), reuse acc ----
    #pragma unroll
    for (int j = 0; j < 16; ++j) acc[j] = 0.f;
    #pragma unroll
    for (int kc = 0; kc < 2; ++kc) {
        v8bf a = *(const v8bf*)(ea32 + (size_t)(e0 + lc)*32 + kc*16 + kh*8);
        v8bf b = *(const v8bf*)(p3 + (size_t)((kc<<2) + wid)*512 + lane*8);
        acc = __builtin_amdgcn_mfma_f32_32x32x16_bf16(a, b, acc, 0, 0, 0);
    }
    {
        const float br = er_b1[col1];
        #pragma unroll
        for (int reg = 0; reg < 16; ++reg) {
            int row = (reg & 3) + 8*(reg >> 2) + 4*kh;
            h2[row*HSTR + col1] = (bf16_t)siluf(acc[reg] + br);
        }
    }
    __syncthreads();

    // ---- GEMM2/4 (K=128, 8 chunks), 3 column-chunk passes; es staged to bf16, then er ----
    #pragma unroll
    for (int ch = 0; ch < 3; ++ch) {
        #pragma unroll
        for (int j = 0; j < 16; ++j) acc[j] = 0.f;
        #pragma unroll
        for (int kc = 0; kc < 8; ++kc) {
            v8bf a1 = *(const v8bf*)&h1[lc*HSTR + kc*16 + kh*8];
            v8bf b1 = *(const v8bf*)(p2 + (size_t)(((ch*8 + kc)<<2) + wid)*512 + lane*8);
            acc = __builtin_amdgcn_mfma_f32_32x32x16_bf16(a1, b1, acc, 0, 0, 0);
        }
        const int col = ch*128 + wid*32 + lc;
        const float be = es_b2[col];
        bf16_t hes[16];
        #pragma unroll
        for (int reg = 0; reg < 16; ++reg) hes[reg] = (bf16_t)(acc[reg] + be);

        #pragma unroll
        for (int j = 0; j < 16; ++j) acc[j] = 0.f;
        #pragma unroll
        for (int kc = 0; kc < 8; ++kc) {
            v8bf a2 = *(const v8bf*)&h2[lc*HSTR + kc*16 + kh*8];
            v8bf b2 = *(const v8bf*)(p4 + (size_t)(((ch*8 + kc)<<2) + wid)*512 + lane*8);
            acc = __builtin_amdgcn_mfma_f32_32x32x16_bf16(a2, b2, acc, 0, 0, 0);
        }
        const float br = er_b2[col];
        // interleaved index: (w1[c],w2[c]) at c*2, c*2+1; (w3[u],w4[u]) at 256+u*2, 257+u*2
        int idx;
        if (ch == 0)      idx = col*2;
        else if (ch == 1) idx = (col - 128)*2 + 1;
        else { int q = col - 256; idx = (q < 64) ? 256 + q*2 : 256 + (q - 64)*2 + 1; }
        #pragma unroll
        for (int reg = 0; reg < 16; ++reg) {
            int row = (reg & 3) + 8*(reg >> 2) + 4*kh;
            int i = e0 + row;
            if (i < E) w_bf[(size_t)i*WNUM + idx] = (bf16_t)((float)hes[reg] * (acc[reg] + br));
        }
    }
}

// ---------------- per-node gather, 4 nodes/block (batched lin2), unroll-4 edge loop ----------------
__global__ __launch_bounds__(192) void k_gather(
    const int* __restrict__ off, const int* __restrict__ send_p,
    const float4* __restrict__ rshs_p,
    const bf16_t* __restrict__ xs_bf, const bf16_t* __restrict__ xv4,
    const bf16_t* __restrict__ w_bf,
    const float* __restrict__ nf,
    const float* __restrict__ w2s, const float* __restrict__ b2s, const float* __restrict__ w2v,
    const float* __restrict__ ln_gs, const float* __restrict__ ln_bs, const float* __restrict__ ln_gv,
    float* __restrict__ out, int N, int E)
{
    __shared__ float accS_l[GNB][192];
    __shared__ float accV_l[GNB][576];
    __shared__ float os_l[GNB][128];
    __shared__ float ov_l[GNB][192];
    __shared__ float stats[GNB][3];
    const int tid = threadIdx.x;
    const int nb = blockIdx.x * GNB;

    for (int nn = 0; nn < GNB; ++nn) {
        int node = nb + nn;
        int i0 = 0, i1 = 0;
        if (node < N) { i0 = off[node]; i1 = off[node+1]; }
        float p0[4], p1a[4], p2a[4], p3a[4];
        #pragma unroll
        for (int u4 = 0; u4 < 4; ++u4) { p0[u4]=0.f; p1a[u4]=0.f; p2a[u4]=0.f; p3a[u4]=0.f; }
        if (tid < 128) {
            const int c = tid;
            int i = i0;
            for (; i + 4 <= i1; i += 4) {
                #pragma unroll
                for (int u4 = 0; u4 < 4; ++u4) {
                    int ii = i + u4;
                    int nsd = send_p[ii];
                    float4 y = rshs_p[ii];
                    v2bf w = *(const v2bf*)(w_bf + (size_t)ii*WNUM + c*2);
                    float xs = (float)xs_bf[(size_t)nsd*NSC + c];
                    p0[u4] += xs * y.x * (float)w[0];
                    float xw = xs * (float)w[1];
                    p1a[u4] += xw * y.y; p2a[u4] += xw * y.z; p3a[u4] += xw * y.w;
                }
            }
            for (; i < i1; ++i) {
                int nsd = send_p[i];
                float4 y = rshs_p[i];
                v2bf w = *(const v2bf*)(w_bf + (size_t)i*WNUM + c*2);
                float xs = (float)xs_bf[(size_t)nsd*NSC + c];
                p0[0] += xs * y.x * (float)w[0];
                float xw = xs * (float)w[1];
                p1a[0] += xw * y.y; p2a[0] += xw * y.z; p3a[0] += xw * y.w;
            }
            float a0 = p0[0]+p0[1]+p0[2]+p0[3];
            float a1 = p1a[0]+p1a[1]+p1a[2]+p1a[3];
            float a2 = p2a[0]+p2a[1]+p2a[2]+p2a[3];
            float a3 = p3a[0]+p3a[1]+p3a[2]+p3a[3];
            accS_l[nn][c] = a0;
            accV_l[nn][c*3+0] = a1; accV_l[nn][c*3+1] = a2; accV_l[nn][c*3+2] = a3;
        } else {
            const int u = tid - 128;
            int i = i0;
            for (; i + 4 <= i1; i += 4) {
                #pragma unroll
                for (int u4 = 0; u4 < 4; ++u4) {
                    int ii = i + u4;
                    int nsd = send_p[ii];
                    float4 y = rshs_p[ii];
                    v2bf w = *(const v2bf*)(w_bf + (size_t)ii*WNUM + 256 + u*2);
                    v4bf xv = *(const v4bf*)(xv4 + (size_t)nsd*256 + u*4);
                    float v0 = (float)xv[0], v1 = (float)xv[1], v2 = (float)xv[2];
                    p0[u4] += (v0*y.y + v1*y.z + v2*y.w) * (float)w[1] * 0.57735026918962576f;
                    float s = y.x * (float)w[0];
                    p1a[u4] += v0*s; p2a[u4] += v1*s; p3a[u4] += v2*s;
                }
            }
            for (; i < i1; ++i) {
                int nsd = send_p[i];
                float4 y = rshs_p[i];
                v2bf w = *(const v2bf*)(w_bf + (size_t)i*WNUM + 256 + u*2);
                v4bf xv = *(const v4bf*)(xv4 + (size_t)nsd*256 + u*4);
                float v0 = (float)xv[0], v1 = (float)xv[1], v2 = (float)xv[2];
                p0[0] += (v0*y.y + v1*y.z + v2*y.w) * (float)w[1] * 0.57735026918962576f;
                float s = y.x * (float)w[0];
                p1a[0] += v0*s; p2a[0] += v1*s; p3a[0] += v2*s;
            }
            float a0 = p0[0]+p0[1]+p0[2]+p0[3];
            float a1 = p1a[0]+p1a[1]+p1a[2]+p1a[3];
            float a2 = p2a[0]+p2a[1]+p2a[2]+p2a[3];
            float a3 = p3a[0]+p3a[1]+p3a[2]+p3a[3];
            accS_l[nn][128+u] = a0;
            accV_l[nn][(128+u)*3+0] = a1; accV_l[nn][(128+u)*3+1] = a2; accV_l[nn][(128+u)*3+2] = a3;
        }
    }
    __syncthreads();

    // lin2 batched over GNB nodes: each weight element loaded once per block
    for (int o = tid; o < 320; o += 192) {
        if (o < 128) {
            float acc[GNB];
            #pragma unroll
            for (int nn = 0; nn < GNB; ++nn) acc[nn] = 0.f;
            for (int c = 0; c < 192; ++c) {
                float w = w2s[c*128 + o];
                #pragma unroll
                for (int nn = 0; nn < GNB; ++nn) acc[nn] += accS_l[nn][c] * w;
            }
            float b = b2s[o];
            #pragma unroll
            for (int nn = 0; nn < GNB; ++nn) os_l[nn][o] = acc[nn] + b;
        } else {
            int q = o - 128;
            int m = q % 3, d = q / 3;
            float acc[GNB];
            #pragma unroll
            for (int nn = 0; nn < GNB; ++nn) acc[nn] = 0.f;
            for (int c = 0; c < 192; ++c) {
                float w = w2v[c*64 + d];
                #pragma unroll
                for (int nn = 0; nn < GNB; ++nn) acc[nn] += accV_l[nn][c*3 + m] * w;
            }
            #pragma unroll
            for (int nn = 0; nn < GNB; ++nn) ov_l[nn][q] = acc[nn];
        }
    }
    __syncthreads();

    // norms: 3 waves cover GNB nodes
    {
        const int lane = tid & 63, wv = tid >> 6;
        for (int nn = wv; nn < GNB; nn += 3) {
            float x0 = os_l[nn][lane], x1 = os_l[nn][lane + 64];
            float s = x0 + x1;
            #pragma unroll
            for (int o = 32; o > 0; o >>= 1) s += __shfl_xor(s, o);
            float mu = s * (1.f/128.f);
            float d0 = x0 - mu, d1 = x1 - mu;
            float q = d0*d0 + d1*d1;
            #pragma unroll
            for (int o = 32; o > 0; o >>= 1) q += __shfl_xor(q, o);
            float var = q * (1.f/128.f);
            float v0 = ov_l[nn][lane], v1 = ov_l[nn][lane + 64], v2 = ov_l[nn][lane + 128];
            float q2 = v0*v0 + v1*v1 + v2*v2;
            #pragma unroll
            for (int o = 32; o > 0; o >>= 1) q2 += __shfl_xor(q2, o);
            float n2 = q2 * (1.f/64.f);
            if (lane == 0) {
                stats[nn][0] = mu;
                stats[nn][1] = rsqrtf(var + 1e-5f);
                stats[nn][2] = rsqrtf(n2 + 1e-5f);
            }
        }
    }
    __syncthreads();

    for (int i = tid; i < GNB*DDIM; i += 192) {
        int nn = i / DDIM, j = i % DDIM;
        int node = nb + nn;
        if (node >= N) continue;
        const float mu = stats[nn][0], rstd = stats[nn][1], rn2 = stats[nn][2];
        const size_t base = (size_t)node * DDIM;
        if (j < 128) {
            out[base + j] = nf[base + j] + (os_l[nn][j] - mu) * rstd * ln_gs[j] + ln_bs[j];
        } else {
            int o = j - 128;
            int d = o / 3;
            out[base + j] = nf[base + j] + ov_l[nn][o] * rn2 * ln_gv[128 + d];
        }
    }
}

static inline size_t align64(size_t x) { return (x + 63) & ~(size_t)63; }

extern "C" void kernel_launch(void* const* d_in, const int* in_sizes, int n_in,
                              void* d_out, int out_size, void* d_ws, size_t ws_size,
                              hipStream_t stream)
{
    const float* nf    = (const float*)d_in[0];
    const float* ea_g  = (const float*)d_in[1];
    const float* rshs  = (const float*)d_in[2];
    const int*   eidx  = (const int*)  d_in[3];
    const float* w0s   = (const float*)d_in[4];
    const float* b0s   = (const float*)d_in[5];
    const float* w0v   = (const float*)d_in[6];
    const float* w1s   = (const float*)d_in[7];
    const float* b1s   = (const float*)d_in[8];
    const float* w1v   = (const float*)d_in[9];
    const float* w2s   = (const float*)d_in[10];
    const float* b2s   = (const float*)d_in[11];
    const float* w2v   = (const float*)d_in[12];
    const float* esw1  = (const float*)d_in[13];
    const float* esb1  = (const float*)d_in[14];
    const float* esw2  = (const float*)d_in[15];
    const float* esb2  = (const float*)d_in[16];
    const float* erw1  = (const float*)d_in[17];
    const float* erb1  = (const float*)d_in[18];
    const float* erw2  = (const float*)d_in[19];
    const float* erb2  = (const float*)d_in[20];
    const float* ln_gs = (const float*)d_in[21];
    const float* ln_bs = (const float*)d_in[22];
    const float* ln_gv = (const float*)d_in[23];

    const int N = in_sizes[0] / DDIM;
    const int E = in_sizes[3] / 2;

    char* p = (char*)d_ws;
    size_t o = 0;
    int* hist = (int*)(p + o);  o = align64(o + (size_t)N * 4);
    int* off  = (int*)(p + o);  o = align64(o + (size_t)(N + 1) * 4);
    int* cnt  = (int*)(p + o);  o = align64(o + (size_t)N * 4);
    int* nsort= (int*)(p + o);  o = align64(o + (size_t)E * 4);
    int* send_p = (int*)(p + o); o = align64(o + (size_t)E * 4);
    float4* rshs_p = (float4*)(p + o); o = align64(o + (size_t)E * 16);
    bf16_t* ea32 = (bf16_t*)(p + o); o = align64(o + (size_t)(E + 64) * 32 * 2);
    bf16_t* ps_bf = (bf16_t*)(p + o); o = align64(o + (size_t)N * 128 * 2);
    bf16_t* pv_bf = (bf16_t*)(p + o); o = align64(o + (size_t)N * 192 * 2);
    bf16_t* xs_bf = (bf16_t*)(p + o); o = align64(o + (size_t)N * 128 * 2);
    bf16_t* xv4  = (bf16_t*)(p + o); o = align64(o + (size_t)N * 256 * 2);
    bf16_t* p1 = (bf16_t*)(p + o); o = align64(o + (size_t)80 * 512 * 2);
    bf16_t* p2 = (bf16_t*)(p + o); o = align64(o + (size_t)96 * 512 * 2);
    bf16_t* p3 = (bf16_t*)(p + o); o = align64(o + (size_t)8  * 512 * 2);
    bf16_t* p4 = (bf16_t*)(p + o); o = align64(o + (size_t)96 * 512 * 2);
    bf16_t* w_bf  = (bf16_t*)(p + o); o = align64(o + (size_t)E * WNUM * 2);

    hipMemsetAsync(hist, 0, (size_t)N * 4, stream);
    k_wconv<<<512, 256, 0, stream>>>(esw1, esw2, erw1, erw2, p1, p2, p3, p4, eidx, hist, E);
    k_nodeprep<<<(N + 15)/16, 256, 0, stream>>>(nf, w0s, b0s, w0v, w1s, b1s, w1v,
                                                ps_bf, pv_bf, xs_bf, xv4, N);
    k_scan<<<1, 1024, 0, stream>>>(hist, off, cnt, N);
    k_scatter<<<512, 256, 0, stream>>>(eidx, rshs, ea_g, cnt,
                                       nsort, send_p, rshs_p, ea32, E);
    k_edge2<<<(E + 31)/32, 256, 0, stream>>>(nsort, send_p, ea32, ps_bf, pv_bf,
                                             p1, p2, p3, p4,
                                             esb1, esb2, erb1, erb2, w_bf, N, E);
    k_gather<<<(N + GNB - 1)/GNB, 192, 0, stream>>>(off, send_p, rshs_p, xs_bf, xv4, w_bf,
                                                    nf, w2s, b2s, w2v, ln_gs, ln_bs, ln_gv,
                                                    (float*)d_out, N, E);
}

// Round 16
// 265.409 us; speedup vs baseline: 1.1453x; 1.0119x over previous
//
#include <hip/hip_runtime.h>
#include <hip/hip_bf16.h>

typedef __bf16 bf16_t;
typedef __bf16 v8bf __attribute__((ext_vector_type(8)));
typedef __bf16 v2bf __attribute__((ext_vector_type(2)));
typedef __bf16 v4bf __attribute__((ext_vector_type(4)));
typedef float  v16f __attribute__((ext_vector_type(16)));

#define NSC   128   // scalar channels
#define NVC   64    // vector channels
#define DDIM  320   // NSC + 3*NVC
#define HIDN  128
#define WNUM  384
#define S0STR 328   // s0 tile stride (656B rows, 16B-aligned)
#define HSTR  136   // h1/h2 stride (272B rows, 16B-aligned)
#define GNB   4     // nodes per gather block

// silu via hardware rcp (v_rcp_f32, ~1 ulp): saves the precise-division expansion
__device__ __forceinline__ float siluf(float x) {
    return x * __builtin_amdgcn_rcpf(1.f + __expf(-x));
}

// ---------------- weight conversion (32x32x16 fragments) + recv histogram ----------------
// B-fragment (32x32x16): lane l holds col n = nt*32 + (l&31), k = kbase + (l>>5)*8 .. +8.
// p1: [kc 0..19][nt 0..3] ; p3: [kc 0..1][nt] ; p2/p4: [ch][kc 0..7][nt]
__global__ void k_wconv(const float* __restrict__ esw1, const float* __restrict__ esw2,
                        const float* __restrict__ erw1, const float* __restrict__ erw2,
                        bf16_t* __restrict__ p1, bf16_t* __restrict__ p2,
                        bf16_t* __restrict__ p3, bf16_t* __restrict__ p4,
                        const int* __restrict__ eidx, int* __restrict__ hist, int E)
{
    const int gid = blockIdx.x * blockDim.x + threadIdx.x;
    const int stride = gridDim.x * blockDim.x;
    for (int i = gid; i < 80*512; i += stride) {
        int frag = i >> 9, q = i & 511, lane = q >> 3, j = q & 7;
        int kc = frag >> 2, nt = frag & 3;
        int n = nt*32 + (lane & 31), k = kc*16 + (lane >> 5)*8 + j;
        p1[i] = (bf16_t)esw1[k*128 + n];
    }
    for (int i = gid; i < 8*512; i += stride) {
        int frag = i >> 9, q = i & 511, lane = q >> 3, j = q & 7;
        int kc = frag >> 2, nt = frag & 3;
        int n = nt*32 + (lane & 31), k = kc*16 + (lane >> 5)*8 + j;
        p3[i] = (k < 20) ? (bf16_t)erw1[k*128 + n] : (bf16_t)(0.f);
    }
    for (int i = gid; i < 96*512; i += stride) {
        int frag = i >> 9, q = i & 511, lane = q >> 3, j = q & 7;
        int ch = frag >> 5, kc = (frag >> 2) & 7, nt = frag & 3;
        int n = ch*128 + nt*32 + (lane & 31), k = kc*16 + (lane >> 5)*8 + j;
        p2[i] = (bf16_t)esw2[k*384 + n];
        p4[i] = (bf16_t)erw2[k*384 + n];
    }
    for (int e = gid; e < E; e += stride)
        atomicAdd(&hist[eidx[e]], 1);
}

__global__ __launch_bounds__(1024) void k_scan(const int* __restrict__ hist,
                                               int* __restrict__ off, int* __restrict__ cnt, int N)
{
    __shared__ int part[1024];
    const int tid = threadIdx.x;
    const int C = (N + 1023) >> 10;
    const int base = tid * C;
    int s = 0;
    for (int j = 0; j < C; ++j) { int idx = base + j; if (idx < N) s += hist[idx]; }
    part[tid] = s;
    __syncthreads();
    for (int d = 1; d < 1024; d <<= 1) {
        int u = (tid >= d) ? part[tid - d] : 0;
        __syncthreads();
        part[tid] += u;
        __syncthreads();
    }
    int run = part[tid] - s;
    for (int j = 0; j < C; ++j) {
        int idx = base + j;
        if (idx < N) { off[idx] = run; cnt[idx] = run; run += hist[idx]; }
    }
    if (tid == 1023) off[N] = part[1023];
}

// ---------------- fused scatter + stream permute (sorted order) ----------------
__global__ void k_scatter(const int* __restrict__ eidx, const float* __restrict__ rshs,
                          const float* __restrict__ ea_g, int* __restrict__ cnt,
                          int* __restrict__ nsort, int* __restrict__ send_p,
                          float4* __restrict__ rshs_p, bf16_t* __restrict__ ea32, int E)
{
    for (int e = blockIdx.x * blockDim.x + threadIdx.x; e < E; e += gridDim.x * blockDim.x) {
        int n = eidx[e];
        int pos = atomicAdd(&cnt[n], 1);
        nsort[pos] = n;
        send_p[pos] = eidx[E + e];
        rshs_p[pos] = *(const float4*)(rshs + (size_t)e*4);
        const float* src = ea_g + (size_t)e*20;
        bf16_t tmp[32];
        #pragma unroll
        for (int j = 0; j < 20; ++j) tmp[j] = (bf16_t)src[j];
        #pragma unroll
        for (int j = 20; j < 32; ++j) tmp[j] = (bf16_t)(0.f);
        bf16_t* dst = ea32 + (size_t)pos*32;
        #pragma unroll
        for (int q = 0; q < 4; ++q)
            *((v8bf*)dst + q) = *((const v8bf*)tmp + q);
    }
}

// ---------------- node prep ----------------
__global__ __launch_bounds__(256) void k_nodeprep(
    const float* __restrict__ nf,
    const float* __restrict__ w0s, const float* __restrict__ b0s, const float* __restrict__ w0v,
    const float* __restrict__ w1s, const float* __restrict__ b1s, const float* __restrict__ w1v,
    bf16_t* __restrict__ ps_bf, bf16_t* __restrict__ pv_bf,
    bf16_t* __restrict__ xs_bf, bf16_t* __restrict__ xv4, int N)
{
    __shared__ float s_in[16][128];
    __shared__ float vt[3][64][16];   // [m][c][node]
    const int tid = threadIdx.x;
    const int nb = blockIdx.x * 16;
    const size_t N64 = (size_t)N * 64;

    for (int idx = tid; idx < 16*320; idx += 256) {
        int n = idx / 320, c = idx % 320;
        int gn = nb + n; if (gn >= N) gn = N - 1;
        float v = nf[(size_t)gn*320 + c];
        if (c < 128) s_in[n][c] = v;
        else { int q = c - 128; vt[q % 3][q / 3][n] = v; }
    }
    __syncthreads();

    {
        const int col = tid & 127, g = tid >> 7;
        float acc[8];
        #pragma unroll
        for (int j = 0; j < 8; ++j) acc[j] = 0.f;
        for (int c4 = 0; c4 < 128; c4 += 4) {
            float wa = w0s[(c4+0)*128 + col];
            float wb = w0s[(c4+1)*128 + col];
            float wc = w0s[(c4+2)*128 + col];
            float wd = w0s[(c4+3)*128 + col];
            #pragma unroll
            for (int j = 0; j < 8; ++j) {
                float4 sv = *(const float4*)&s_in[g*8+j][c4];
                acc[j] += sv.x*wa + sv.y*wb + sv.z*wc + sv.w*wd;
            }
        }
        float b = b0s[col];
        #pragma unroll
        for (int j = 0; j < 8; ++j) {
            int gn = nb + g*8 + j;
            if (gn < N) ps_bf[(size_t)gn*128 + col] = (bf16_t)(acc[j] + b);
        }
    }
    if (tid < 192) {
        const int d = tid & 63, m = tid >> 6;
        float acc[16];
        #pragma unroll
        for (int j = 0; j < 16; ++j) acc[j] = 0.f;
        for (int c = 0; c < 64; ++c) {
            float w = w0v[c*64 + d];
            float4 a0 = *(const float4*)&vt[m][c][0];
            float4 a1 = *(const float4*)&vt[m][c][4];
            float4 a2 = *(const float4*)&vt[m][c][8];
            float4 a3 = *(const float4*)&vt[m][c][12];
            acc[0]+=a0.x*w; acc[1]+=a0.y*w; acc[2]+=a0.z*w; acc[3]+=a0.w*w;
            acc[4]+=a1.x*w; acc[5]+=a1.y*w; acc[6]+=a1.z*w; acc[7]+=a1.w*w;
            acc[8]+=a2.x*w; acc[9]+=a2.y*w; acc[10]+=a2.z*w; acc[11]+=a2.w*w;
            acc[12]+=a3.x*w; acc[13]+=a3.y*w; acc[14]+=a3.z*w; acc[15]+=a3.w*w;
        }
        #pragma unroll
        for (int j = 0; j < 16; ++j) {
            int gn = nb + j;
            if (gn < N) pv_bf[(size_t)m*N64 + (size_t)gn*64 + d] = (bf16_t)acc[j];
        }
    }
    __syncthreads();

    for (int idx = tid; idx < 2048; idx += 256) {
        int n = idx >> 7, c = idx & 127;
        s_in[n][c] = siluf(s_in[n][c]);
    }
    for (int idx = tid; idx < 1024; idx += 256) {
        int n = idx & 15, cc = idx >> 4;
        float v0 = vt[0][cc][n], v1 = vt[1][cc][n], v2 = vt[2][cc][n];
        float nn = sqrtf(v0*v0 + v1*v1 + v2*v2 + 1e-10f);
        float sc = __builtin_amdgcn_rcpf(1.f + __expf(-nn));   // silu(n)/n = sigmoid(n)
        vt[0][cc][n] = v0*sc; vt[1][cc][n] = v1*sc; vt[2][cc][n] = v2*sc;
    }
    __syncthreads();

    {
        const int col = tid & 127, g = tid >> 7;
        float acc[8];
        #pragma unroll
        for (int j = 0; j < 8; ++j) acc[j] = 0.f;
        for (int c4 = 0; c4 < 128; c4 += 4) {
            float wa = w1s[(c4+0)*128 + col];
            float wb = w1s[(c4+1)*128 + col];
            float wc = w1s[(c4+2)*128 + col];
            float wd = w1s[(c4+3)*128 + col];
            #pragma unroll
            for (int j = 0; j < 8; ++j) {
                float4 sv = *(const float4*)&s_in[g*8+j][c4];
                acc[j] += sv.x*wa + sv.y*wb + sv.z*wc + sv.w*wd;
            }
        }
        float b = b1s[col];
        #pragma unroll
        for (int j = 0; j < 8; ++j) {
            int gn = nb + g*8 + j;
            if (gn < N) xs_bf[(size_t)gn*128 + col] = (bf16_t)(acc[j] + b);
        }
    }
    if (tid < 192) {
        const int d = tid & 63, m = tid >> 6;
        float acc[16];
        #pragma unroll
        for (int j = 0; j < 16; ++j) acc[j] = 0.f;
        for (int c = 0; c < 64; ++c) {
            float w = w1v[c*64 + d];
            float4 a0 = *(const float4*)&vt[m][c][0];
            float4 a1 = *(const float4*)&vt[m][c][4];
            float4 a2 = *(const float4*)&vt[m][c][8];
            float4 a3 = *(const float4*)&vt[m][c][12];
            acc[0]+=a0.x*w; acc[1]+=a0.y*w; acc[2]+=a0.z*w; acc[3]+=a0.w*w;
            acc[4]+=a1.x*w; acc[5]+=a1.y*w; acc[6]+=a1.z*w; acc[7]+=a1.w*w;
            acc[8]+=a2.x*w; acc[9]+=a2.y*w; acc[10]+=a2.z*w; acc[11]+=a2.w*w;
            acc[12]+=a3.x*w; acc[13]+=a3.y*w; acc[14]+=a3.z*w; acc[15]+=a3.w*w;
        }
        // xv4 layout: [node][64][4] (4th slot unused)
        #pragma unroll
        for (int j = 0; j < 16; ++j) {
            int gn = nb + j;
            if (gn < N) xv4[(size_t)gn*256 + d*4 + m] = (bf16_t)acc[j];
        }
    }
}

// ---------------- edge MLP: 32-edge tile, 4 waves, 32x32x16 MFMA, ONE live accumulator ----------------
// 3 barriers (wave-local recv/send load removes the first), uniform bounds-check hoist.
__global__ __launch_bounds__(256) void k_edge2(
    const int* __restrict__ nsort, const int* __restrict__ send_p,
    const bf16_t* __restrict__ ea32,
    const bf16_t* __restrict__ ps_bf, const bf16_t* __restrict__ pv_bf,
    const bf16_t* __restrict__ p1, const bf16_t* __restrict__ p2,
    const bf16_t* __restrict__ p3, const bf16_t* __restrict__ p4,
    const float* __restrict__ es_b1, const float* __restrict__ es_b2,
    const float* __restrict__ er_b1, const float* __restrict__ er_b2,
    bf16_t* __restrict__ w_bf, int N, int E)
{
    __shared__ __align__(16) bf16_t s0h[32*S0STR];   // s0 tile; reused for h1/h2
    __shared__ int   recv_l[32], send_l[32];

    const int tid  = threadIdx.x;
    const int lane = tid & 63;
    const int wid  = tid >> 6;     // 0..3 = this wave's 32-col group
    const int e0   = blockIdx.x * 32;
    const bool full = (e0 + 32 <= E);
    const size_t N64 = (size_t)N * 64;

    // wave-local: this wave writes and reads only its own 8 entries -> no barrier needed
    if (lane < 8) {
        int i = e0 + wid*8 + lane; if (i >= E) i = E - 1;
        recv_l[wid*8 + lane] = nsort[i];
        send_l[wid*8 + lane] = send_p[i];
    }

    #pragma unroll
    for (int rr = 0; rr < 8; ++rr) {
        int r = wid*8 + rr;
        int nr = recv_l[r], nsd = send_l[r];
        if (lane < 32) {
            *(uint2*)&s0h[r*S0STR + lane*4] = *(const uint2*)(ps_bf + (size_t)nr*NSC + lane*4);
        } else {
            int l2 = lane - 32;
            *(uint2*)&s0h[r*S0STR + 128 + l2*4] = *(const uint2*)(ps_bf + (size_t)nsd*NSC + l2*4);
        }
        float d = 0.f;
        #pragma unroll
        for (int m = 0; m < 3; ++m)
            d += (float)pv_bf[m*N64 + (size_t)nr*64 + lane] * (float)pv_bf[m*N64 + (size_t)nsd*64 + lane];
        s0h[r*S0STR + 256 + lane] = (bf16_t)d;
    }
    __syncthreads();

    const int lc = lane & 31;      // A row / B col within 32
    const int kh = lane >> 5;      // k half (0/1) -> k offset kh*8
    bf16_t* h1 = s0h;              // 32 x HSTR
    bf16_t* h2 = s0h + 32*HSTR;
    const int col1 = wid*32 + lc;

    v16f acc;

    // ---- GEMM1 (K=320, 20 chunks) ----
    #pragma unroll
    for (int j = 0; j < 16; ++j) acc[j] = 0.f;
    {
        const bf16_t* aB = &s0h[lc*S0STR + kh*8];
        #pragma unroll
        for (int kc = 0; kc < 20; ++kc) {
            v8bf a = *(const v8bf*)(aB + kc*16);
            v8bf b = *(const v8bf*)(p1 + (size_t)((kc<<2) + wid)*512 + lane*8);
            acc = __builtin_amdgcn_mfma_f32_32x32x16_bf16(a, b, acc, 0, 0, 0);
        }
    }
    __syncthreads();   // all s0h reads done; safe to overwrite with h1/h2

    {
        const float be = es_b1[col1];
        #pragma unroll
        for (int reg = 0; reg < 16; ++reg) {
            int row = (reg & 3) + 8*(reg >> 2) + 4*kh;
            h1[row*HSTR + col1] = (bf16_t)siluf(acc[reg] + be);
        }
    }

    // ---- GEMM3 (K=32, 2 chunks), reuse acc ----
    #pragma unroll
    for (int j = 0; j < 16; ++j) acc[j] = 0.f;
    #pragma unroll
    for (int kc = 0; kc < 2; ++kc) {
        v8bf a = *(const v8bf*)(ea32 + (size_t)(e0 + lc)*32 + kc*16 + kh*8);
        v8bf b = *(const v8bf*)(p3 + (size_t)((kc<<2) + wid)*512 + lane*8);
        acc = __builtin_amdgcn_mfma_f32_32x32x16_bf16(a, b, acc, 0, 0, 0);
    }
    {
        const float br = er_b1[col1];
        #pragma unroll
        for (int reg = 0; reg < 16; ++reg) {
            int row = (reg & 3) + 8*(reg >> 2) + 4*kh;
            h2[row*HSTR + col1] = (bf16_t)siluf(acc[reg] + br);
        }
    }
    __syncthreads();

    // ---- GEMM2/4 (K=128, 8 chunks), 3 column-chunk passes; es staged to bf16, then er ----
    #pragma unroll
    for (int ch = 0; ch < 3; ++ch) {
        #pragma unroll
        for (int j = 0; j < 16; ++j) acc[j] = 0.f;
        #pragma unroll
        for (int kc = 0; kc < 8; ++kc) {
            v8bf a1 = *(const v8bf*)&h1[lc*HSTR + kc*16 + kh*8];
            v8bf b1 = *(const v8bf*)(p2 + (size_t)(((ch*8 + kc)<<2) + wid)*512 + lane*8);
            acc = __builtin_amdgcn_mfma_f32_32x32x16_bf16(a1, b1, acc, 0, 0, 0);
        }
        const int col = ch*128 + wid*32 + lc;
        const float be = es_b2[col];
        bf16_t hes[16];
        #pragma unroll
        for (int reg = 0; reg < 16; ++reg) hes[reg] = (bf16_t)(acc[reg] + be);

        #pragma unroll
        for (int j = 0; j < 16; ++j) acc[j] = 0.f;
        #pragma unroll
        for (int kc = 0; kc < 8; ++kc) {
            v8bf a2 = *(const v8bf*)&h2[lc*HSTR + kc*16 + kh*8];
            v8bf b2 = *(const v8bf*)(p4 + (size_t)(((ch*8 + kc)<<2) + wid)*512 + lane*8);
            acc = __builtin_amdgcn_mfma_f32_32x32x16_bf16(a2, b2, acc, 0, 0, 0);
        }
        const float br = er_b2[col];
        // interleaved index: (w1[c],w2[c]) at c*2, c*2+1; (w3[u],w4[u]) at 256+u*2, 257+u*2
        int idx;
        if (ch == 0)      idx = col*2;
        else if (ch == 1) idx = (col - 128)*2 + 1;
        else { int q = col - 256; idx = (q < 64) ? 256 + q*2 : 256 + (q - 64)*2 + 1; }
        if (full) {
            #pragma unroll
            for (int reg = 0; reg < 16; ++reg) {
                int row = (reg & 3) + 8*(reg >> 2) + 4*kh;
                w_bf[(size_t)(e0 + row)*WNUM + idx] = (bf16_t)((float)hes[reg] * (acc[reg] + br));
            }
        } else {
            #pragma unroll
            for (int reg = 0; reg < 16; ++reg) {
                int row = (reg & 3) + 8*(reg >> 2) + 4*kh;
                int i = e0 + row;
                if (i < E) w_bf[(size_t)i*WNUM + idx] = (bf16_t)((float)hes[reg] * (acc[reg] + br));
            }
        }
    }
}

// ---------------- per-node gather, 4 nodes/block (batched lin2), unroll-4 edge loop ----------------
__global__ __launch_bounds__(192) void k_gather(
    const int* __restrict__ off, const int* __restrict__ send_p,
    const float4* __restrict__ rshs_p,
    const bf16_t* __restrict__ xs_bf, const bf16_t* __restrict__ xv4,
    const bf16_t* __restrict__ w_bf,
    const float* __restrict__ nf,
    const float* __restrict__ w2s, const float* __restrict__ b2s, const float* __restrict__ w2v,
    const float* __restrict__ ln_gs, const float* __restrict__ ln_bs, const float* __restrict__ ln_gv,
    float* __restrict__ out, int N, int E)
{
    __shared__ float accS_l[GNB][192];
    __shared__ float accV_l[GNB][576];
    __shared__ float os_l[GNB][128];
    __shared__ float ov_l[GNB][192];
    __shared__ float stats[GNB][3];
    const int tid = threadIdx.x;
    const int nb = blockIdx.x * GNB;

    for (int nn = 0; nn < GNB; ++nn) {
        int node = nb + nn;
        int i0 = 0, i1 = 0;
        if (node < N) { i0 = off[node]; i1 = off[node+1]; }
        float p0[4], p1a[4], p2a[4], p3a[4];
        #pragma unroll
        for (int u4 = 0; u4 < 4; ++u4) { p0[u4]=0.f; p1a[u4]=0.f; p2a[u4]=0.f; p3a[u4]=0.f; }
        if (tid < 128) {
            const int c = tid;
            int i = i0;
            for (; i + 4 <= i1; i += 4) {
                #pragma unroll
                for (int u4 = 0; u4 < 4; ++u4) {
                    int ii = i + u4;
                    int nsd = send_p[ii];
                    float4 y = rshs_p[ii];
                    v2bf w = *(const v2bf*)(w_bf + (size_t)ii*WNUM + c*2);
                    float xs = (float)xs_bf[(size_t)nsd*NSC + c];
                    p0[u4] += xs * y.x * (float)w[0];
                    float xw = xs * (float)w[1];
                    p1a[u4] += xw * y.y; p2a[u4] += xw * y.z; p3a[u4] += xw * y.w;
                }
            }
            for (; i < i1; ++i) {
                int nsd = send_p[i];
                float4 y = rshs_p[i];
                v2bf w = *(const v2bf*)(w_bf + (size_t)i*WNUM + c*2);
                float xs = (float)xs_bf[(size_t)nsd*NSC + c];
                p0[0] += xs * y.x * (float)w[0];
                float xw = xs * (float)w[1];
                p1a[0] += xw * y.y; p2a[0] += xw * y.z; p3a[0] += xw * y.w;
            }
            float a0 = p0[0]+p0[1]+p0[2]+p0[3];
            float a1 = p1a[0]+p1a[1]+p1a[2]+p1a[3];
            float a2 = p2a[0]+p2a[1]+p2a[2]+p2a[3];
            float a3 = p3a[0]+p3a[1]+p3a[2]+p3a[3];
            accS_l[nn][c] = a0;
            accV_l[nn][c*3+0] = a1; accV_l[nn][c*3+1] = a2; accV_l[nn][c*3+2] = a3;
        } else {
            const int u = tid - 128;
            int i = i0;
            for (; i + 4 <= i1; i += 4) {
                #pragma unroll
                for (int u4 = 0; u4 < 4; ++u4) {
                    int ii = i + u4;
                    int nsd = send_p[ii];
                    float4 y = rshs_p[ii];
                    v2bf w = *(const v2bf*)(w_bf + (size_t)ii*WNUM + 256 + u*2);
                    v4bf xv = *(const v4bf*)(xv4 + (size_t)nsd*256 + u*4);
                    float v0 = (float)xv[0], v1 = (float)xv[1], v2 = (float)xv[2];
                    p0[u4] += (v0*y.y + v1*y.z + v2*y.w) * (float)w[1] * 0.57735026918962576f;
                    float s = y.x * (float)w[0];
                    p1a[u4] += v0*s; p2a[u4] += v1*s; p3a[u4] += v2*s;
                }
            }
            for (; i < i1; ++i) {
                int nsd = send_p[i];
                float4 y = rshs_p[i];
                v2bf w = *(const v2bf*)(w_bf + (size_t)i*WNUM + 256 + u*2);
                v4bf xv = *(const v4bf*)(xv4 + (size_t)nsd*256 + u*4);
                float v0 = (float)xv[0], v1 = (float)xv[1], v2 = (float)xv[2];
                p0[0] += (v0*y.y + v1*y.z + v2*y.w) * (float)w[1] * 0.57735026918962576f;
                float s = y.x * (float)w[0];
                p1a[0] += v0*s; p2a[0] += v1*s; p3a[0] += v2*s;
            }
            float a0 = p0[0]+p0[1]+p0[2]+p0[3];
            float a1 = p1a[0]+p1a[1]+p1a[2]+p1a[3];
            float a2 = p2a[0]+p2a[1]+p2a[2]+p2a[3];
            float a3 = p3a[0]+p3a[1]+p3a[2]+p3a[3];
            accS_l[nn][128+u] = a0;
            accV_l[nn][(128+u)*3+0] = a1; accV_l[nn][(128+u)*3+1] = a2; accV_l[nn][(128+u)*3+2] = a3;
        }
    }
    __syncthreads();

    // lin2 batched over GNB nodes: each weight element loaded once per block
    for (int o = tid; o < 320; o += 192) {
        if (o < 128) {
            float acc[GNB];
            #pragma unroll
            for (int nn = 0; nn < GNB; ++nn) acc[nn] = 0.f;
            for (int c = 0; c < 192; ++c) {
                float w = w2s[c*128 + o];
                #pragma unroll
                for (int nn = 0; nn < GNB; ++nn) acc[nn] += accS_l[nn][c] * w;
            }
            float b = b2s[o];
            #pragma unroll
            for (int nn = 0; nn < GNB; ++nn) os_l[nn][o] = acc[nn] + b;
        } else {
            int q = o - 128;
            int m = q % 3, d = q / 3;
            float acc[GNB];
            #pragma unroll
            for (int nn = 0; nn < GNB; ++nn) acc[nn] = 0.f;
            for (int c = 0; c < 192; ++c) {
                float w = w2v[c*64 + d];
                #pragma unroll
                for (int nn = 0; nn < GNB; ++nn) acc[nn] += accV_l[nn][c*3 + m] * w;
            }
            #pragma unroll
            for (int nn = 0; nn < GNB; ++nn) ov_l[nn][q] = acc[nn];
        }
    }
    __syncthreads();

    // norms: 3 waves cover GNB nodes
    {
        const int lane = tid & 63, wv = tid >> 6;
        for (int nn = wv; nn < GNB; nn += 3) {
            float x0 = os_l[nn][lane], x1 = os_l[nn][lane + 64];
            float s = x0 + x1;
            #pragma unroll
            for (int o = 32; o > 0; o >>= 1) s += __shfl_xor(s, o);
            float mu = s * (1.f/128.f);
            float d0 = x0 - mu, d1 = x1 - mu;
            float q = d0*d0 + d1*d1;
            #pragma unroll
            for (int o = 32; o > 0; o >>= 1) q += __shfl_xor(q, o);
            float var = q * (1.f/128.f);
            float v0 = ov_l[nn][lane], v1 = ov_l[nn][lane + 64], v2 = ov_l[nn][lane + 128];
            float q2 = v0*v0 + v1*v1 + v2*v2;
            #pragma unroll
            for (int o = 32; o > 0; o >>= 1) q2 += __shfl_xor(q2, o);
            float n2 = q2 * (1.f/64.f);
            if (lane == 0) {
                stats[nn][0] = mu;
                stats[nn][1] = rsqrtf(var + 1e-5f);
                stats[nn][2] = rsqrtf(n2 + 1e-5f);
            }
        }
    }
    __syncthreads();

    for (int i = tid; i < GNB*DDIM; i += 192) {
        int nn = i / DDIM, j = i % DDIM;
        int node = nb + nn;
        if (node >= N) continue;
        const float mu = stats[nn][0], rstd = stats[nn][1], rn2 = stats[nn][2];
        const size_t base = (size_t)node * DDIM;
        if (j < 128) {
            out[base + j] = nf[base + j] + (os_l[nn][j] - mu) * rstd * ln_gs[j] + ln_bs[j];
        } else {
            int o = j - 128;
            int d = o / 3;
            out[base + j] = nf[base + j] + ov_l[nn][o] * rn2 * ln_gv[128 + d];
        }
    }
}

static inline size_t align64(size_t x) { return (x + 63) & ~(size_t)63; }

extern "C" void kernel_launch(void* const* d_in, const int* in_sizes, int n_in,
                              void* d_out, int out_size, void* d_ws, size_t ws_size,
                              hipStream_t stream)
{
    const float* nf    = (const float*)d_in[0];
    const float* ea_g  = (const float*)d_in[1];
    const float* rshs  = (const float*)d_in[2];
    const int*   eidx  = (const int*)  d_in[3];
    const float* w0s   = (const float*)d_in[4];
    const float* b0s   = (const float*)d_in[5];
    const float* w0v   = (const float*)d_in[6];
    const float* w1s   = (const float*)d_in[7];
    const float* b1s   = (const float*)d_in[8];
    const float* w1v   = (const float*)d_in[9];
    const float* w2s   = (const float*)d_in[10];
    const float* b2s   = (const float*)d_in[11];
    const float* w2v   = (const float*)d_in[12];
    const float* esw1  = (const float*)d_in[13];
    const float* esb1  = (const float*)d_in[14];
    const float* esw2  = (const float*)d_in[15];
    const float* esb2  = (const float*)d_in[16];
    const float* erw1  = (const float*)d_in[17];
    const float* erb1  = (const float*)d_in[18];
    const float* erw2  = (const float*)d_in[19];
    const float* erb2  = (const float*)d_in[20];
    const float* ln_gs = (const float*)d_in[21];
    const float* ln_bs = (const float*)d_in[22];
    const float* ln_gv = (const float*)d_in[23];

    const int N = in_sizes[0] / DDIM;
    const int E = in_sizes[3] / 2;

    char* p = (char*)d_ws;
    size_t o = 0;
    int* hist = (int*)(p + o);  o = align64(o + (size_t)N * 4);
    int* off  = (int*)(p + o);  o = align64(o + (size_t)(N + 1) * 4);
    int* cnt  = (int*)(p + o);  o = align64(o + (size_t)N * 4);
    int* nsort= (int*)(p + o);  o = align64(o + (size_t)E * 4);
    int* send_p = (int*)(p + o); o = align64(o + (size_t)E * 4);
    float4* rshs_p = (float4*)(p + o); o = align64(o + (size_t)E * 16);
    bf16_t* ea32 = (bf16_t*)(p + o); o = align64(o + (size_t)(E + 64) * 32 * 2);
    bf16_t* ps_bf = (bf16_t*)(p + o); o = align64(o + (size_t)N * 128 * 2);
    bf16_t* pv_bf = (bf16_t*)(p + o); o = align64(o + (size_t)N * 192 * 2);
    bf16_t* xs_bf = (bf16_t*)(p + o); o = align64(o + (size_t)N * 128 * 2);
    bf16_t* xv4  = (bf16_t*)(p + o); o = align64(o + (size_t)N * 256 * 2);
    bf16_t* p1 = (bf16_t*)(p + o); o = align64(o + (size_t)80 * 512 * 2);
    bf16_t* p2 = (bf16_t*)(p + o); o = align64(o + (size_t)96 * 512 * 2);
    bf16_t* p3 = (bf16_t*)(p + o); o = align64(o + (size_t)8  * 512 * 2);
    bf16_t* p4 = (bf16_t*)(p + o); o = align64(o + (size_t)96 * 512 * 2);
    bf16_t* w_bf  = (bf16_t*)(p + o); o = align64(o + (size_t)E * WNUM * 2);

    hipMemsetAsync(hist, 0, (size_t)N * 4, stream);
    k_wconv<<<512, 256, 0, stream>>>(esw1, esw2, erw1, erw2, p1, p2, p3, p4, eidx, hist, E);
    k_nodeprep<<<(N + 15)/16, 256, 0, stream>>>(nf, w0s, b0s, w0v, w1s, b1s, w1v,
                                                ps_bf, pv_bf, xs_bf, xv4, N);
    k_scan<<<1, 1024, 0, stream>>>(hist, off, cnt, N);
    k_scatter<<<512, 256, 0, stream>>>(eidx, rshs, ea_g, cnt,
                                       nsort, send_p, rshs_p, ea32, E);
    k_edge2<<<(E + 31)/32, 256, 0, stream>>>(nsort, send_p, ea32, ps_bf, pv_bf,
                                             p1, p2, p3, p4,
                                             esb1, esb2, erb1, erb2, w_bf, N, E);
    k_gather<<<(N + GNB - 1)/GNB, 192, 0, stream>>>(off, send_p, rshs_p, xs_bf, xv4, w_bf,
                                                    nf, w2s, b2s, w2v, ln_gs, ln_bs, ln_gv,
                                                    (float*)d_out, N, E);
}